// Round 2
// baseline (109.288 us; speedup 1.0000x reference)
//
#include <hip/hip_runtime.h>
#include <hip/hip_bf16.h>
#include <math.h>

// Problem constants (fixed by setup_inputs): B=128, P=4096, L=128
#define BB 128
#define PP 4096
#define LL 128
#define BLOCK 256
#define CHUNKS (PP / BLOCK)   // 16 blocks per batch
#define SCALE 32.0f

__global__ void zero_out_kernel(float* out) { out[0] = 0.0f; }

__global__ __launch_bounds__(BLOCK) void classifier_loss_kernel(
    const float* __restrict__ cls,     // [B, 2P]
    const float* __restrict__ bbox,    // [B, 4P]
    const float* __restrict__ roi,     // [B, P, 4]
    const float* __restrict__ labels,  // [B, L, 4]
    const int* __restrict__ neg_enabled,
    float* __restrict__ out)
{
    // s_lab: raw (x, y, w, h); s_ext: (x2, y2, area, unused)
    __shared__ float s_lab[LL][4];
    __shared__ float s_ext[LL][4];
    __shared__ float s_red[BLOCK / 64];

    const int b     = blockIdx.x / CHUNKS;
    const int chunk = blockIdx.x % CHUNKS;
    const int p     = chunk * BLOCK + threadIdx.x;

    // Stage this batch's labels into LDS with scalar loads (no alignment assumptions)
    if (threadIdx.x < LL) {
        const float* lp = labels + ((size_t)b * LL + threadIdx.x) * 4;
        float lx = lp[0], ly = lp[1], lw = lp[2], lh = lp[3];
        s_lab[threadIdx.x][0] = lx;
        s_lab[threadIdx.x][1] = ly;
        s_lab[threadIdx.x][2] = lw;
        s_lab[threadIdx.x][3] = lh;
        s_ext[threadIdx.x][0] = lx + lw;
        s_ext[threadIdx.x][1] = ly + lh;
        s_ext[threadIdx.x][2] = lw * lh;
        s_ext[threadIdx.x][3] = 0.0f;
    }
    __syncthreads();

    // Proposal box in image coords (scalar loads, no alignment assumptions)
    const float* rp = roi + ((size_t)b * PP + p) * 4;
    const float rx = rp[0] * SCALE, ry = rp[1] * SCALE;
    const float rw = rp[2] * SCALE, rh = rp[3] * SCALE;
    const float rx2 = rx + rw, ry2 = ry + rh;
    const float rarea = rw * rh;

    // --- argmax IoU over labels, division-free (union > 0 always) ---
    float best_inter, best_union;
    int   best_idx = 0;
    {
        float ix = fmaxf(0.0f, fminf(s_ext[0][0], rx2) - fmaxf(s_lab[0][0], rx));
        float iy = fmaxf(0.0f, fminf(s_ext[0][1], ry2) - fmaxf(s_lab[0][1], ry));
        best_inter = ix * iy;
        best_union = s_ext[0][2] + rarea - best_inter;
    }
    #pragma unroll 4
    for (int li = 1; li < LL; ++li) {
        float ix = fmaxf(0.0f, fminf(s_ext[li][0], rx2) - fmaxf(s_lab[li][0], rx));
        float iy = fmaxf(0.0f, fminf(s_ext[li][1], ry2) - fmaxf(s_lab[li][1], ry));
        float inter = ix * iy;
        float uni   = s_ext[li][2] + rarea - inter;
        // iou_li > iou_best  <=>  inter*best_union > best_inter*uni (all >= 0, unions > 0)
        bool gt = inter * best_union > best_inter * uni;
        best_inter = gt ? inter : best_inter;
        best_union = gt ? uni   : best_union;
        best_idx   = gt ? li    : best_idx;
    }

    const bool any_hit = best_inter > 0.0f;           // max iou != 0
    const bool pos     = any_hit && (best_idx > 0);   // ref: match > 0

    // --- classification CE (softmax over 2 classes) ---
    const float s0 = cls[(size_t)b * 2 * PP + p];
    const float s1 = cls[(size_t)b * 2 * PP + PP + p];
    const float mx = fmaxf(s0, s1);
    const float e0 = expf(s0 - mx);
    const float e1 = expf(s1 - mx);
    const float inv = 1.0f / (e0 + e1);
    const float p0 = e0 * inv, p1 = e1 * inv;
    const float LOG01 = -2.3025850929940457f;  // log(0.1)
    const float LOG09 = -0.10536051565782628f; // log(0.9)
    const float ce_pos = -(p0 * LOG01 + p1 * LOG09);
    const float ce_neg = -(p0 * LOG09 + p1 * LOG01);

    float per;
    if (pos) {
        float mxl = s_lab[best_idx][0];
        float myl = s_lab[best_idx][1];
        float mwl = s_lab[best_idx][2];
        float mhl = s_lab[best_idx][3];
        float tx = (mxl - rx) / rw;
        float ty = (myl - ry) / rh;
        float tw = logf(fmaxf(mwl / rw, 1e-8f));
        float th = logf(fmaxf(mhl / rh, 1e-8f));
        // preds: bbox_deltas[b, c*P + p]
        const float* bp = bbox + (size_t)b * 4 * PP + p;
        float px = bp[0];
        float py = bp[PP];
        float pw = bp[2 * PP];
        float ph = bp[3 * PP];
        float ex = tx - px, ey = ty - py, ew = tw - pw, eh = th - ph;
        float ax = fabsf(ex), ay = fabsf(ey), aw = fabsf(ew), ah = fabsf(eh);
        float hx = (ax <= 1.0f) ? 0.5f * ex * ex : ax - 0.5f;
        float hy = (ay <= 1.0f) ? 0.5f * ey * ey : ay - 0.5f;
        float hw = (aw <= 1.0f) ? 0.5f * ew * ew : aw - 0.5f;
        float hh = (ah <= 1.0f) ? 0.5f * eh * eh : ah - 0.5f;
        float huber = 0.25f * (hx + hy + hw + hh);
        per = 2.0f * huber + ce_pos;
    } else {
        per = (neg_enabled[0] > 0) ? ce_neg : 0.0f;
    }

    // --- reduce: wave64 shuffle -> LDS -> one atomic per block ---
    float v = per;
    #pragma unroll
    for (int off = 32; off > 0; off >>= 1)
        v += __shfl_down(v, off, 64);
    if ((threadIdx.x & 63) == 0)
        s_red[threadIdx.x >> 6] = v;
    __syncthreads();
    if (threadIdx.x == 0) {
        float blk = s_red[0] + s_red[1] + s_red[2] + s_red[3];
        atomicAdd(out, blk);
    }
}

extern "C" void kernel_launch(void* const* d_in, const int* in_sizes, int n_in,
                              void* d_out, int out_size, void* d_ws, size_t ws_size,
                              hipStream_t stream) {
    const float* cls    = (const float*)d_in[0];
    const float* bbox   = (const float*)d_in[1];
    const float* roi    = (const float*)d_in[2];
    const float* labels = (const float*)d_in[3];
    const int*   neg    = (const int*)d_in[4];
    float* out = (float*)d_out;

    zero_out_kernel<<<1, 1, 0, stream>>>(out);
    classifier_loss_kernel<<<dim3(BB * CHUNKS), dim3(BLOCK), 0, stream>>>(
        cls, bbox, roi, labels, neg, out);
}